// Round 1
// baseline (102.882 us; speedup 1.0000x reference)
//
#include <hip/hip_runtime.h>
#include <hip/hip_bf16.h>

// Shapes: B=128, N=64, P=128, T=168
// x: [128,64,128] f32, x_i: [128,128] i32, g: [4096,4096] f32,
// weights: [4096,1] f32, alphas: [1,168] f32
// Out: Z [128,64] (8192 f32) then F [4096,168] (688128 f32), concat flat.

#define GN 4096
#define TT 168
#define BB 128
#define NN 64
#define PP 128

// Kernel 1: v[row] = sum_j g[row,j] * w[j]^2 ; F[row,t] = v[row]*alphas[t]
__global__ __launch_bounds__(256) void k_rowdot(
    const float* __restrict__ g, const float* __restrict__ w,
    const float* __restrict__ alphas, float* __restrict__ v,
    float* __restrict__ Fout) {
  const int row = blockIdx.x;      // 0..4095
  const int t = threadIdx.x;       // 0..255
  const float4* g4 = (const float4*)(g + (size_t)row * GN);
  const float4* w4 = (const float4*)w;
  float s = 0.f;
#pragma unroll
  for (int it = 0; it < 4; ++it) {
    int idx = t + it * 256;        // 1024 float4 per row
    float4 a = g4[idx];
    float4 b = w4[idx];
    s += a.x * (b.x * b.x) + a.y * (b.y * b.y) + a.z * (b.z * b.z) + a.w * (b.w * b.w);
  }
  // wave (64-lane) reduction
#pragma unroll
  for (int off = 32; off > 0; off >>= 1) s += __shfl_down(s, off, 64);
  __shared__ float ls[4];
  __shared__ float vsh;
  const int wave = t >> 6, lane = t & 63;
  if (lane == 0) ls[wave] = s;
  __syncthreads();
  if (t == 0) {
    float vi = ls[0] + ls[1] + ls[2] + ls[3];
    v[row] = vi;
    vsh = vi;
  }
  __syncthreads();
  const float vi = vsh;
  if (t < TT) Fout[(size_t)row * TT + t] = vi * alphas[t];
}

// Kernel 2: per block b:
//   ap[p] = alphas[x_i[b,p]]
//   y[j]  = sum_p ap[p] * x[b,j,p]
//   Z[b,i]= sum_j v[i*64+j] * y[j]
__global__ __launch_bounds__(256) void k_z(
    const float* __restrict__ x, const int* __restrict__ xi,
    const float* __restrict__ alphas, const float* __restrict__ v,
    float* __restrict__ Z) {
  const int b = blockIdx.x;        // 0..127
  const int t = threadIdx.x;       // 0..255
  __shared__ float ap[PP];
  __shared__ float y[NN];
  if (t < PP) ap[t] = alphas[xi[b * PP + t]];
  __syncthreads();
  // 4 threads per j; thread r handles p = r + 4k
  const int j = t >> 2, r = t & 3;
  const float* xrow = x + (size_t)b * (NN * PP) + (size_t)j * PP;
  float s = 0.f;
#pragma unroll
  for (int k = 0; k < 32; ++k) {
    int p = r + 4 * k;
    s += ap[p] * xrow[p];
  }
  // reduce the quad (lanes 4j..4j+3 are within one 64-lane wave)
  s += __shfl_down(s, 2, 64);
  s += __shfl_down(s, 1, 64);
  if (r == 0) y[j] = s;
  __syncthreads();
  if (t < NN) {
    const float* vrow = v + t * NN;
    float z = 0.f;
#pragma unroll
    for (int jj = 0; jj < NN; ++jj) z += vrow[jj] * y[jj];
    Z[b * NN + t] = z;
  }
}

extern "C" void kernel_launch(void* const* d_in, const int* in_sizes, int n_in,
                              void* d_out, int out_size, void* d_ws, size_t ws_size,
                              hipStream_t stream) {
  const float* x      = (const float*)d_in[0];   // [128,64,128]
  const int*   xi     = (const int*)  d_in[1];   // [128,128]
  const float* g      = (const float*)d_in[2];   // [4096,4096]
  const float* w      = (const float*)d_in[3];   // [4096,1]
  const float* alphas = (const float*)d_in[4];   // [1,168]

  float* Z    = (float*)d_out;                   // [128,64]
  float* Fout = (float*)d_out + (BB * NN);       // [4096,168]
  float* v    = (float*)d_ws;                    // [4096] scratch

  k_rowdot<<<GN, 256, 0, stream>>>(g, w, alphas, v, Fout);
  k_z<<<BB, 256, 0, stream>>>(x, xi, alphas, v, Z);
}